// Round 9
// baseline (1092.176 us; speedup 1.0000x reference)
//
#include <hip/hip_runtime.h>
#include <hip/hip_bf16.h>
#include <math.h>

#define N_NODES 50000
#define N_EDGES 800000
#define NUM_GRAPHS 500
#define F_IN 128
#define HID 256
#define NCLS 10

typedef _Float16 f16;
typedef _Float16 f16x8 __attribute__((ext_vector_type(8)));
typedef _Float16 f16x4 __attribute__((ext_vector_type(4)));
typedef float f32x4 __attribute__((ext_vector_type(4)));

// Dual-plane interleaved (DPI) layout: a [R][K] fp32 matrix is stored as f16
// records of 2K: elem(r,k).hi at r*2K + (k>>7)*256 + (k&127), .lo at +128.
// Every 128-feature half is a contiguous 512 B block [hi128|lo128].

// ---------------- fp32 x -> DPI (K=128) ----------------
__global__ __launch_bounds__(256) void split_f32(const float* __restrict__ in,
                                                 f16* __restrict__ out, int n4) {
  int i = blockIdx.x * 256 + threadIdx.x;
  if (i < n4) {
    float4 v = ((const float4*)in)[i];
    int row = i >> 5, j = i & 31;  // 32 float4 per 128-wide row
    f16x4 h, l;
    f16 h0 = (f16)v.x; h[0] = h0; l[0] = (f16)(v.x - (float)h0);
    f16 h1 = (f16)v.y; h[1] = h1; l[1] = (f16)(v.y - (float)h1);
    f16 h2 = (f16)v.z; h[2] = h2; l[2] = (f16)(v.z - (float)h2);
    f16 h3 = (f16)v.w; h[3] = h3; l[3] = (f16)(v.w - (float)h3);
    ((f16x4*)out)[row * 64 + j] = h;       // hi block
    ((f16x4*)out)[row * 64 + 32 + j] = l;  // lo block
  }
}

// -------- weight transpose+split: W[b][K][Mc] -> DPI T[(b*Mc+m)][2K] ---------
__global__ __launch_bounds__(256) void tsplit(const float* __restrict__ W,
                                              f16* __restrict__ T,
                                              int K, int Mc, int total) {
  int tid = blockIdx.x * 256 + threadIdx.x;
  if (tid < total) {
    int km = K * Mc;
    int b = tid / km;
    int rem = tid - b * km;
    int m = rem / K;
    int k = rem - m * K;
    float v = W[(size_t)b * km + (size_t)k * Mc + m];
    f16 h = (f16)v;
    size_t o = (size_t)(b * Mc + m) * (2 * K) + ((k >> 7) << 8) + (k & 127);
    T[o] = h;
    T[o + 128] = (f16)(v - (float)h);
  }
}

// ---------------- MFMA GEMM (f16x2 emulation) on DPI, no LDS/barriers --------
// C[M,Nc] = A[M,K] @ B[K,Nc]; B given transposed+DPI as Wt[Nc][2K].
// 4 waves (2x2), wave tile 64x64, 4x4 frags of 16x16x32 MFMA.
__global__ __launch_bounds__(256) void gemm_mfma(
    const f16* __restrict__ Act, const f16* __restrict__ Wt,
    const float* __restrict__ bias, f16* __restrict__ Cout,
    int M, int K, int Nc) {
  const int lane = threadIdx.x & 63;
  const int wave = threadIdx.x >> 6;
  const int wm = wave >> 1;
  const int wn = wave & 1;
  const int row0 = blockIdx.x * 128 + wm * 64;
  const int col0 = blockIdx.y * 128 + wn * 64;
  const int lr = lane & 15;
  const int kg = (lane >> 4) * 8;
  const int K2 = 2 * K;

  f32x4 acc[4][4];
  const f32x4 vzero = {0.f, 0.f, 0.f, 0.f};
#pragma unroll
  for (int m = 0; m < 4; ++m)
#pragma unroll
    for (int n = 0; n < 4; ++n) acc[m][n] = vzero;

  size_t aoff[4], boff[4];
#pragma unroll
  for (int m = 0; m < 4; ++m) {
    int r = row0 + m * 16 + lr;
    if (r > M - 1) r = M - 1;  // clamp tail reads (writes guarded below)
    aoff[m] = (size_t)r * K2;
  }
#pragma unroll
  for (int n = 0; n < 4; ++n)
    boff[n] = (size_t)(col0 + n * 16 + lr) * K2;

#pragma unroll 1
  for (int k0 = 0; k0 < K; k0 += 32) {
    int kk = k0 + kg;
    int off = ((kk >> 7) << 8) + (kk & 127);
    f16x8 ah[4], al[4], bh[4], bl[4];
#pragma unroll
    for (int m = 0; m < 4; ++m) {
      ah[m] = *(const f16x8*)(Act + aoff[m] + off);
      al[m] = *(const f16x8*)(Act + aoff[m] + off + 128);
    }
#pragma unroll
    for (int n = 0; n < 4; ++n) {
      bh[n] = *(const f16x8*)(Wt + boff[n] + off);
      bl[n] = *(const f16x8*)(Wt + boff[n] + off + 128);
    }
#pragma unroll
    for (int m = 0; m < 4; ++m)
#pragma unroll
      for (int n = 0; n < 4; ++n) {
        acc[m][n] = __builtin_amdgcn_mfma_f32_16x16x32_f16(ah[m], bh[n], acc[m][n], 0, 0, 0);
        acc[m][n] = __builtin_amdgcn_mfma_f32_16x16x32_f16(ah[m], bl[n], acc[m][n], 0, 0, 0);
        acc[m][n] = __builtin_amdgcn_mfma_f32_16x16x32_f16(al[m], bh[n], acc[m][n], 0, 0, 0);
      }
  }

  const int rbase = (lane >> 4) * 4;
  const int Nc2 = 2 * Nc;
#pragma unroll
  for (int m = 0; m < 4; ++m) {
#pragma unroll
    for (int r = 0; r < 4; ++r) {
      int row = row0 + m * 16 + rbase + r;
      if (row < M) {
#pragma unroll
        for (int n = 0; n < 4; ++n) {
          int col = col0 + n * 16 + lr;
          float v = acc[m][n][r];
          if (bias) v += bias[col];
          f16 h = (f16)v;
          size_t o = (size_t)row * Nc2 + ((col >> 7) << 8) + (col & 127);
          Cout[o] = h;
          Cout[o + 128] = (f16)(v - (float)h);
        }
      }
    }
  }
}

// ---------------- degree accumulation ----------------
__global__ __launch_bounds__(256) void deg_accum(
    const int* __restrict__ dst, const float* __restrict__ ew,
    float* deg, int* cnt, int E) {
  int e = blockIdx.x * 256 + threadIdx.x;
  if (e < E) {
    int d = dst[e];
    atomicAdd(&deg[d], ew[e]);
    atomicAdd(&cnt[d], 1);
  }
}

// ---------------- hierarchical exclusive scan + dinv ----------------
__global__ __launch_bounds__(256) void scan_p1(const int* __restrict__ cnt,
                                               const float* __restrict__ deg,
                                               float* __restrict__ dinv,
                                               int* __restrict__ bsum, int n) {
  __shared__ int s[256];
  int i = blockIdx.x * 256 + threadIdx.x;
  s[threadIdx.x] = (i < n) ? cnt[i] : 0;
  if (i < n) dinv[i] = rsqrtf(deg[i] + 1.0f);
  __syncthreads();
  for (int off = 128; off > 0; off >>= 1) {
    if (threadIdx.x < off) s[threadIdx.x] += s[threadIdx.x + off];
    __syncthreads();
  }
  if (threadIdx.x == 0) bsum[blockIdx.x] = s[0];
}

__global__ __launch_bounds__(256) void scan_p2(int* __restrict__ bsum, int nb,
                                               int* __restrict__ total_out) {
  __shared__ int s[256];
  int t = threadIdx.x;
  int v = (t < nb) ? bsum[t] : 0;
  s[t] = v;
  __syncthreads();
  for (int off = 1; off < 256; off <<= 1) {
    int u = (t >= off) ? s[t - off] : 0;
    __syncthreads();
    s[t] += u;
    __syncthreads();
  }
  if (t < nb) bsum[t] = s[t] - v;
  if (t == 255) *total_out = s[255];
}

__global__ __launch_bounds__(256) void scan_p3(const int* __restrict__ cnt,
                                               const int* __restrict__ bsum,
                                               int* __restrict__ row_ptr, int n) {
  __shared__ int s[256];
  int i = blockIdx.x * 256 + threadIdx.x;
  int t = threadIdx.x;
  int v = (i < n) ? cnt[i] : 0;
  s[t] = v;
  __syncthreads();
  for (int off = 1; off < 256; off <<= 1) {
    int u = (t >= off) ? s[t - off] : 0;
    __syncthreads();
    s[t] += u;
    __syncthreads();
  }
  if (i < n) row_ptr[i] = bsum[blockIdx.x] + s[t] - v;
}

// ---------------- CSR fill ----------------
__global__ __launch_bounds__(256) void csr_fill(
    const int* __restrict__ src, const int* __restrict__ dst,
    const float* __restrict__ ew, const float* __restrict__ dinv,
    const int* __restrict__ row_ptr, int* cursor,
    int* __restrict__ csr_src, float* __restrict__ csr_coef, int E) {
  int e = blockIdx.x * 256 + threadIdx.x;
  if (e < E) {
    int s = src[e], d = dst[e];
    int pos = atomicAdd(&cursor[d], 1);
    int idx = row_ptr[d] + pos;
    csr_src[idx] = s;
    csr_coef[idx] = dinv[s] * ew[e] * dinv[d];
  }
}

// -- aggregation + bias + ELU over one 128-feature half (DPI record 512 B) ----
// lanes 0-31 accumulate hi-plane, lanes 32-63 the lo-plane of the SAME
// features; one shfl_xor(32) combines; every lane writes its own 8 B back.
__global__ __launch_bounds__(256) void gather_elu(
    const f16* __restrict__ Act, const float* __restrict__ dinv,
    const int* __restrict__ row_ptr, const int* __restrict__ csr_src,
    const float* __restrict__ csr_coef, const float* __restrict__ bias,
    f16* __restrict__ Out, int half) {
  const int wave = threadIdx.x >> 6;
  const int lane = threadIdx.x & 63;
  const int n = blockIdx.x * 4 + wave;
  if (n >= N_NODES) return;
  const size_t lofs = (size_t)(half << 8) + (lane << 2);  // f16 units in record
  const int start = row_ptr[n], end = row_ptr[n + 1];
  const float di = dinv[n];
  const float cself = di * di;
  f16x4 sv = *(const f16x4*)(Act + (size_t)n * 512 + lofs);
  float a0 = cself * (float)sv[0];
  float a1 = cself * (float)sv[1];
  float a2 = cself * (float)sv[2];
  float a3 = cself * (float)sv[3];
  const int npairs = (end - start) >> 1;
  int e = start;
  if (npairs > 0) {
    int s0 = csr_src[e], s1 = csr_src[e + 1];
    float w0 = csr_coef[e], w1 = csr_coef[e + 1];
    for (int p = 1; p < npairs; ++p) {
      e += 2;
      f16x4 v0 = *(const f16x4*)(Act + (size_t)s0 * 512 + lofs);
      f16x4 v1 = *(const f16x4*)(Act + (size_t)s1 * 512 + lofs);
      int t0 = csr_src[e], t1 = csr_src[e + 1];
      float u0 = csr_coef[e], u1 = csr_coef[e + 1];
      a0 += w0 * (float)v0[0] + w1 * (float)v1[0];
      a1 += w0 * (float)v0[1] + w1 * (float)v1[1];
      a2 += w0 * (float)v0[2] + w1 * (float)v1[2];
      a3 += w0 * (float)v0[3] + w1 * (float)v1[3];
      s0 = t0; s1 = t1; w0 = u0; w1 = u1;
    }
    f16x4 v0 = *(const f16x4*)(Act + (size_t)s0 * 512 + lofs);
    f16x4 v1 = *(const f16x4*)(Act + (size_t)s1 * 512 + lofs);
    a0 += w0 * (float)v0[0] + w1 * (float)v1[0];
    a1 += w0 * (float)v0[1] + w1 * (float)v1[1];
    a2 += w0 * (float)v0[2] + w1 * (float)v1[2];
    a3 += w0 * (float)v0[3] + w1 * (float)v1[3];
    e += 2;
  }
  if (e < end) {
    int s0 = csr_src[e];
    float w0 = csr_coef[e];
    f16x4 v0 = *(const f16x4*)(Act + (size_t)s0 * 512 + lofs);
    a0 += w0 * (float)v0[0];
    a1 += w0 * (float)v0[1];
    a2 += w0 * (float)v0[2];
    a3 += w0 * (float)v0[3];
  }
  // combine hi-lane and lo-lane partial sums (identical in both partners)
  a0 += __shfl_xor(a0, 32);
  a1 += __shfl_xor(a1, 32);
  a2 += __shfl_xor(a2, 32);
  a3 += __shfl_xor(a3, 32);
  float4 bb = ((const float4*)bias)[(half << 5) + (lane & 31)];
  a0 += bb.x; a1 += bb.y; a2 += bb.z; a3 += bb.w;
  a0 = (a0 > 0.f) ? a0 : expm1f(a0);
  a1 = (a1 > 0.f) ? a1 : expm1f(a1);
  a2 = (a2 > 0.f) ? a2 : expm1f(a2);
  a3 = (a3 > 0.f) ? a3 : expm1f(a3);
  f16x4 o;
  f16 q0 = (f16)a0, q1 = (f16)a1, q2 = (f16)a2, q3 = (f16)a3;
  if (lane < 32) {
    o[0] = q0; o[1] = q1; o[2] = q2; o[3] = q3;
  } else {
    o[0] = (f16)(a0 - (float)q0);
    o[1] = (f16)(a1 - (float)q1);
    o[2] = (f16)(a2 - (float)q2);
    o[3] = (f16)(a3 - (float)q3);
  }
  *(f16x4*)(Out + (size_t)n * 512 + lofs) = o;
}

// ---------------- pooling (sorted batch -> ranges) + final linear -------------
__global__ __launch_bounds__(256) void find_start(const int* __restrict__ batch,
                                                  int* __restrict__ gstart) {
  int g = blockIdx.x * 256 + threadIdx.x;
  if (g <= NUM_GRAPHS) {
    int lo = 0, hi = N_NODES;
    while (lo < hi) {
      int mid = (lo + hi) >> 1;
      if (batch[mid] < g) lo = mid + 1; else hi = mid;
    }
    gstart[g] = lo;
  }
}

__global__ __launch_bounds__(256) void pool_final(
    const f16* __restrict__ Act, const int* __restrict__ gstart,
    const float* __restrict__ W, const float* __restrict__ b,
    float* __restrict__ out) {
  int g = blockIdx.x;
  __shared__ float part[NCLS * 256];
  int f = threadIdx.x;
  int s = gstart[g], e = gstart[g + 1];
  int base = ((f >> 7) << 8) + (f & 127);
  float sum = 0.f;
  for (int n = s; n < e; ++n) {
    size_t o = (size_t)n * 512 + base;
    sum += (float)Act[o] + (float)Act[o + 128];
  }
  float v = sum / fmaxf((float)(e - s), 1.0f);
#pragma unroll
  for (int c = 0; c < NCLS; ++c) part[c * 256 + f] = v * W[f * NCLS + c];
  __syncthreads();
  for (int off = 128; off > 0; off >>= 1) {
    if (f < off) {
#pragma unroll
      for (int c = 0; c < NCLS; ++c) part[c * 256 + f] += part[c * 256 + f + off];
    }
    __syncthreads();
  }
  if (f < NCLS) out[g * NCLS + f] = part[f * 256] + b[f];
}

extern "C" void kernel_launch(void* const* d_in, const int* in_sizes, int n_in,
                              void* d_out, int out_size, void* d_ws, size_t ws_size,
                              hipStream_t stream) {
  const float* x = (const float*)d_in[0];
  const int* ei = (const int*)d_in[1];
  const int* e_src = ei;
  const int* e_dst = ei + N_EDGES;
  const float* ea = (const float*)d_in[2];
  // d_in[3] = edge_type: unused (edge_dim=1 mixing carries no per-type params)
  const int* batch = (const int*)d_in[4];
  const float* enc1_w = (const float*)d_in[5];
  const float* enc1_b = (const float*)d_in[6];
  const float* enc2_w = (const float*)d_in[7];
  const float* enc2_b = (const float*)d_in[8];
  const float* conv_ws = (const float*)d_in[9];
  const float* conv_bs = (const float*)d_in[10];
  const float* lin1_w = (const float*)d_in[11];
  const float* lin1_b = (const float*)d_in[12];
  float* out = (float*)d_out;

  char* w = (char*)d_ws;
  size_t off = 0;
  auto alloc = [&](size_t bytes) {
    size_t o = off;
    off = (off + bytes + 255) & ~(size_t)255;
    return (void*)(w + o);
  };
  // activation DPI buffers: 50000 records x 512 f16 (256 feats hi+lo)
  f16* Aact = (f16*)alloc((size_t)N_NODES * 512 * 2);
  f16* Bact = (f16*)alloc((size_t)N_NODES * 512 * 2);
  // DPI weights: enc1 128x256, enc2 256x256, conv 4x 256x512 (f16 counts)
  f16* wt = (f16*)alloc((size_t)(32768 + 65536 + 4 * 131072) * 2);
  float* deg = (float*)alloc((size_t)N_NODES * 4);
  float* dinv = (float*)alloc((size_t)N_NODES * 4);
  int* cnt = (int*)alloc((size_t)N_NODES * 4);
  int* row_ptr = (int*)alloc((size_t)(N_NODES + 1) * 4);
  int* cursor = (int*)alloc((size_t)N_NODES * 4);
  int* bsum = (int*)alloc((size_t)256 * 4);
  int* csr_src = (int*)alloc((size_t)N_EDGES * 4);
  float* csr_coef = (float*)alloc((size_t)N_EDGES * 4);
  int* gstart = (int*)alloc((size_t)(NUM_GRAPHS + 1) * 4);
  (void)ws_size; (void)in_sizes; (void)n_in; (void)out_size;

  hipMemsetAsync(deg, 0, (size_t)N_NODES * 4, stream);
  hipMemsetAsync(cnt, 0, (size_t)N_NODES * 4, stream);
  hipMemsetAsync(cursor, 0, (size_t)N_NODES * 4, stream);

  const int nb_nodes = (N_NODES + 255) / 256;
  const int nb_edges = (N_EDGES + 255) / 256;

  // graph normalization + CSR (feature-independent)
  deg_accum<<<nb_edges, 256, 0, stream>>>(e_dst, ea, deg, cnt, N_EDGES);
  scan_p1<<<nb_nodes, 256, 0, stream>>>(cnt, deg, dinv, bsum, N_NODES);
  scan_p2<<<1, 256, 0, stream>>>(bsum, nb_nodes, row_ptr + N_NODES);
  scan_p3<<<nb_nodes, 256, 0, stream>>>(cnt, bsum, row_ptr, N_NODES);
  csr_fill<<<nb_edges, 256, 0, stream>>>(e_src, e_dst, ea, dinv, row_ptr, cursor,
                                         csr_src, csr_coef, N_EDGES);
  find_start<<<(NUM_GRAPHS + 256) / 256, 256, 0, stream>>>(batch, gstart);

  // split x (DPI K=128) into Bact front region (dead after enc1)
  f16* xdpi = Bact;
  {
    int n4 = N_NODES * F_IN / 4;
    split_f32<<<(n4 + 255) / 256, 256, 0, stream>>>(x, xdpi, n4);
  }
  // weight transpose+split (DPI)
  f16* e1t = wt;                  // 128 rows x 2*128
  f16* e2t = wt + 32768;          // 256 rows x 2*128
  f16* cvt_ = wt + 32768 + 65536; // 4 x (256 rows x 2*256)
  tsplit<<<(16384 + 255) / 256, 256, 0, stream>>>(enc1_w, e1t, F_IN, F_IN, 16384);
  tsplit<<<(32768 + 255) / 256, 256, 0, stream>>>(enc2_w, e2t, F_IN, HID, 32768);
  tsplit<<<(262144 + 255) / 256, 256, 0, stream>>>(conv_ws, cvt_, HID, HID, 262144);

  const int gR = (N_NODES + 127) / 128;  // 391
  const int gGather = (N_NODES + 3) / 4; // 12500

  // enc1: x@W1+b1 -> Aact (128-feat DPI)
  {
    dim3 grid(gR, 1);
    gemm_mfma<<<grid, 256, 0, stream>>>(xdpi, e1t, enc1_b, Aact,
                                        N_NODES, F_IN, F_IN);
  }
  // enc2: h0@W2+b2 -> Bact (256-feat DPI; overwrites dead x region)
  {
    dim3 grid(gR, 2);
    gemm_mfma<<<grid, 256, 0, stream>>>(Aact, e2t, enc2_b, Bact,
                                        N_NODES, F_IN, HID);
  }

  // 4 GCN layers: hW = h@W (B->A); aggregate+bias+ELU per half (A->B)
  for (int layer = 0; layer < 4; ++layer) {
    dim3 grid(gR, 2);
    gemm_mfma<<<grid, 256, 0, stream>>>(Bact, cvt_ + (size_t)layer * 131072,
                                        nullptr, Aact, N_NODES, HID, HID);
    // two sequential half-passes: 25 MB working set each (L2 reuse)
    gather_elu<<<gGather, 256, 0, stream>>>(
        Aact, dinv, row_ptr, csr_src, csr_coef,
        conv_bs + (size_t)layer * HID, Bact, 0);
    gather_elu<<<gGather, 256, 0, stream>>>(
        Aact, dinv, row_ptr, csr_src, csr_coef,
        conv_bs + (size_t)layer * HID, Bact, 1);
  }

  // deterministic mean-pool per graph + final linear (fused)
  pool_final<<<NUM_GRAPHS, 256, 0, stream>>>(Bact, gstart, lin1_w, lin1_b, out);
}

// Round 10
// 810.103 us; speedup vs baseline: 1.3482x; 1.3482x over previous
//
#include <hip/hip_runtime.h>
#include <hip/hip_bf16.h>
#include <math.h>

#define N_NODES 50000
#define N_EDGES 800000
#define NUM_GRAPHS 500
#define F_IN 128
#define HID 256
#define NCLS 10

typedef _Float16 f16;
typedef _Float16 f16x8 __attribute__((ext_vector_type(8)));
typedef _Float16 f16x4 __attribute__((ext_vector_type(4)));
typedef float f32x4 __attribute__((ext_vector_type(4)));

#define LOW40 ((1ULL << 40) - 1)

// ---------------- fp32 -> (hi,lo) f16 split, elementwise (float4/thread) ------
__global__ __launch_bounds__(256) void split_f32(const float* __restrict__ in,
                                                 f16* __restrict__ hi,
                                                 f16* __restrict__ lo, int n4) {
  int i = blockIdx.x * 256 + threadIdx.x;
  if (i < n4) {
    float4 v = ((const float4*)in)[i];
    f16x4 h, l;
    f16 h0 = (f16)v.x; h[0] = h0; l[0] = (f16)(v.x - (float)h0);
    f16 h1 = (f16)v.y; h[1] = h1; l[1] = (f16)(v.y - (float)h1);
    f16 h2 = (f16)v.z; h[2] = h2; l[2] = (f16)(v.z - (float)h2);
    f16 h3 = (f16)v.w; h[3] = h3; l[3] = (f16)(v.w - (float)h3);
    ((f16x4*)hi)[i] = h;
    ((f16x4*)lo)[i] = l;
  }
}

// -------- weight transpose + split: W[b][K][Mc] -> T[b][Mc][K] (hi,lo) --------
__global__ __launch_bounds__(256) void tsplit(const float* __restrict__ W,
                                              f16* __restrict__ Th,
                                              f16* __restrict__ Tl,
                                              int K, int Mc, int total) {
  int tid = blockIdx.x * 256 + threadIdx.x;
  if (tid < total) {
    int km = K * Mc;
    int b = tid / km;
    int rem = tid - b * km;
    int m = rem / K;
    int k = rem - m * K;
    float v = W[(size_t)b * km + (size_t)k * Mc + m];
    f16 h = (f16)v;
    Th[tid] = h;
    Tl[tid] = (f16)(v - (float)h);
  }
}

// ---------------- MFMA GEMM (f16x2 emulation), no LDS, no barriers ------------
// C = (Ah+Al) @ (Bh+Bl) ~ ah*bh + ah*bl + al*bh ; Bt transposed [Nc][K].
// 4 waves (2x2), wave tile 64x64, 4x4 frags of 16x16x32 MFMA.
__global__ __launch_bounds__(256) void gemm_mfma(
    const f16* __restrict__ Ah, const f16* __restrict__ Al,
    const f16* __restrict__ Bth, const f16* __restrict__ Btl,
    const float* __restrict__ bias,
    f16* __restrict__ Ch, f16* __restrict__ Cl,
    int M, int K, int Nc) {
  const int lane = threadIdx.x & 63;
  const int wave = threadIdx.x >> 6;
  const int wm = wave >> 1;
  const int wn = wave & 1;
  const int row0 = blockIdx.x * 128 + wm * 64;
  const int col0 = blockIdx.y * 128 + wn * 64;
  const int lr = lane & 15;
  const int kg = (lane >> 4) * 8;

  f32x4 acc[4][4];
  const f32x4 vzero = {0.f, 0.f, 0.f, 0.f};
#pragma unroll
  for (int m = 0; m < 4; ++m)
#pragma unroll
    for (int n = 0; n < 4; ++n) acc[m][n] = vzero;

  size_t aoff[4], boff[4];
#pragma unroll
  for (int m = 0; m < 4; ++m) {
    int r = row0 + m * 16 + lr;
    if (r > M - 1) r = M - 1;  // clamp tail reads (writes guarded below)
    aoff[m] = (size_t)r * K + kg;
  }
#pragma unroll
  for (int n = 0; n < 4; ++n)
    boff[n] = (size_t)(col0 + n * 16 + lr) * K + kg;

#pragma unroll 1
  for (int k0 = 0; k0 < K; k0 += 32) {
    f16x8 ah[4], al[4], bh[4], bl[4];
#pragma unroll
    for (int m = 0; m < 4; ++m) {
      ah[m] = *(const f16x8*)(Ah + aoff[m] + k0);
      al[m] = *(const f16x8*)(Al + aoff[m] + k0);
    }
#pragma unroll
    for (int n = 0; n < 4; ++n) {
      bh[n] = *(const f16x8*)(Bth + boff[n] + k0);
      bl[n] = *(const f16x8*)(Btl + boff[n] + k0);
    }
#pragma unroll
    for (int m = 0; m < 4; ++m)
#pragma unroll
      for (int n = 0; n < 4; ++n) {
        acc[m][n] = __builtin_amdgcn_mfma_f32_16x16x32_f16(ah[m], bh[n], acc[m][n], 0, 0, 0);
        acc[m][n] = __builtin_amdgcn_mfma_f32_16x16x32_f16(ah[m], bl[n], acc[m][n], 0, 0, 0);
        acc[m][n] = __builtin_amdgcn_mfma_f32_16x16x32_f16(al[m], bh[n], acc[m][n], 0, 0, 0);
      }
  }

  const int rbase = (lane >> 4) * 4;
#pragma unroll
  for (int m = 0; m < 4; ++m) {
#pragma unroll
    for (int r = 0; r < 4; ++r) {
      int row = row0 + m * 16 + rbase + r;
      if (row < M) {
#pragma unroll
        for (int n = 0; n < 4; ++n) {
          int col = col0 + n * 16 + lr;
          float v = acc[m][n][r];
          if (bias) v += bias[col];
          f16 h = (f16)v;
          size_t o = (size_t)row * Nc + col;
          Ch[o] = h;
          Cl[o] = (f16)(v - (float)h);
        }
      }
    }
  }
}

// ------- degree accumulation: ONE packed u64 atomic per edge ----------------
// bits [63:40] = count, bits [39:0] = sum(ew * 2^24) fixed-point
__global__ __launch_bounds__(256) void deg_accum(
    const int* __restrict__ dst, const float* __restrict__ ew,
    unsigned long long* __restrict__ dpack, int E) {
  int e = blockIdx.x * 256 + threadIdx.x;
  if (e < E) {
    unsigned long long v = (1ULL << 40) |
        (unsigned long long)(unsigned)(ew[e] * 16777216.0f + 0.5f);
    atomicAdd(&dpack[dst[e]], v);
  }
}

// ---------------- hierarchical exclusive scan + dinv (from packed) -----------
__global__ __launch_bounds__(256) void scan_p1(
    const unsigned long long* __restrict__ dpack,
    float* __restrict__ dinv, int* __restrict__ bsum, int n) {
  __shared__ int s[256];
  int i = blockIdx.x * 256 + threadIdx.x;
  int c = 0;
  if (i < n) {
    unsigned long long v = dpack[i];
    c = (int)(v >> 40);
    float d = (float)(v & LOW40) * (1.0f / 16777216.0f);
    dinv[i] = rsqrtf(d + 1.0f);  // + self-loop weight, always > 0
  }
  s[threadIdx.x] = c;
  __syncthreads();
  for (int off = 128; off > 0; off >>= 1) {
    if (threadIdx.x < off) s[threadIdx.x] += s[threadIdx.x + off];
    __syncthreads();
  }
  if (threadIdx.x == 0) bsum[blockIdx.x] = s[0];
}

__global__ __launch_bounds__(256) void scan_p2(int* __restrict__ bsum, int nb,
                                               int* __restrict__ total_out) {
  __shared__ int s[256];
  int t = threadIdx.x;
  int v = (t < nb) ? bsum[t] : 0;
  s[t] = v;
  __syncthreads();
  for (int off = 1; off < 256; off <<= 1) {
    int u = (t >= off) ? s[t - off] : 0;
    __syncthreads();
    s[t] += u;
    __syncthreads();
  }
  if (t < nb) bsum[t] = s[t] - v;
  if (t == 255) *total_out = s[255];
}

__global__ __launch_bounds__(256) void scan_p3(
    const unsigned long long* __restrict__ dpack,
    const int* __restrict__ bsum, int* __restrict__ row_ptr, int n) {
  __shared__ int s[256];
  int i = blockIdx.x * 256 + threadIdx.x;
  int t = threadIdx.x;
  int v = (i < n) ? (int)(dpack[i] >> 40) : 0;
  s[t] = v;
  __syncthreads();
  for (int off = 1; off < 256; off <<= 1) {
    int u = (t >= off) ? s[t - off] : 0;
    __syncthreads();
    s[t] += u;
    __syncthreads();
  }
  if (i < n) row_ptr[i] = bsum[blockIdx.x] + s[t] - v;
}

// ---------------- CSR fill ----------------
__global__ __launch_bounds__(256) void csr_fill(
    const int* __restrict__ src, const int* __restrict__ dst,
    const float* __restrict__ ew, const float* __restrict__ dinv,
    const int* __restrict__ row_ptr, int* cursor,
    int* __restrict__ csr_src, float* __restrict__ csr_coef, int E) {
  int e = blockIdx.x * 256 + threadIdx.x;
  if (e < E) {
    int s = src[e], d = dst[e];
    int pos = atomicAdd(&cursor[d], 1);
    int idx = row_ptr[d] + pos;
    csr_src[idx] = s;
    csr_coef[idx] = dinv[s] * ew[e] * dinv[d];
  }
}

// -- aggregation + bias + ELU: neighbors read HI PLANE ONLY (halves traffic) --
// self term uses hi+lo (exact); output written as hi+lo planes.
__global__ __launch_bounds__(256) void gather_elu(
    const f16* __restrict__ Hh, const f16* __restrict__ Hl,
    const float* __restrict__ dinv, const int* __restrict__ row_ptr,
    const int* __restrict__ csr_src, const float* __restrict__ csr_coef,
    const float* __restrict__ bias,
    f16* __restrict__ Oh, f16* __restrict__ Ol) {
  const int wave = threadIdx.x >> 6;
  const int lane = threadIdx.x & 63;
  const int n = blockIdx.x * 4 + wave;
  if (n >= N_NODES) return;
  const f16x4* hh4 = (const f16x4*)Hh;  // 64 f16x4 per row
  const int start = row_ptr[n], end = row_ptr[n + 1];
  const float di = dinv[n];
  const float cself = di * di;
  size_t self = (size_t)n * 64 + lane;
  f16x4 sh = hh4[self];
  f16x4 sl = ((const f16x4*)Hl)[self];
  float a0 = cself * ((float)sh[0] + (float)sl[0]);
  float a1 = cself * ((float)sh[1] + (float)sl[1]);
  float a2 = cself * ((float)sh[2] + (float)sl[2]);
  float a3 = cself * ((float)sh[3] + (float)sl[3]);
  const int npairs = (end - start) >> 1;
  int e = start;
  if (npairs > 0) {
    int s0 = csr_src[e], s1 = csr_src[e + 1];
    float w0 = csr_coef[e], w1 = csr_coef[e + 1];
    for (int p = 1; p < npairs; ++p) {
      e += 2;
      f16x4 v0 = hh4[(size_t)s0 * 64 + lane];
      f16x4 v1 = hh4[(size_t)s1 * 64 + lane];
      int t0 = csr_src[e], t1 = csr_src[e + 1];
      float u0 = csr_coef[e], u1 = csr_coef[e + 1];
      a0 += w0 * (float)v0[0] + w1 * (float)v1[0];
      a1 += w0 * (float)v0[1] + w1 * (float)v1[1];
      a2 += w0 * (float)v0[2] + w1 * (float)v1[2];
      a3 += w0 * (float)v0[3] + w1 * (float)v1[3];
      s0 = t0; s1 = t1; w0 = u0; w1 = u1;
    }
    f16x4 v0 = hh4[(size_t)s0 * 64 + lane];
    f16x4 v1 = hh4[(size_t)s1 * 64 + lane];
    a0 += w0 * (float)v0[0] + w1 * (float)v1[0];
    a1 += w0 * (float)v0[1] + w1 * (float)v1[1];
    a2 += w0 * (float)v0[2] + w1 * (float)v1[2];
    a3 += w0 * (float)v0[3] + w1 * (float)v1[3];
    e += 2;
  }
  if (e < end) {
    int s0 = csr_src[e];
    float w0 = csr_coef[e];
    f16x4 v0 = hh4[(size_t)s0 * 64 + lane];
    a0 += w0 * (float)v0[0];
    a1 += w0 * (float)v0[1];
    a2 += w0 * (float)v0[2];
    a3 += w0 * (float)v0[3];
  }
  float4 bb = ((const float4*)bias)[lane];
  a0 += bb.x; a1 += bb.y; a2 += bb.z; a3 += bb.w;
  a0 = (a0 > 0.f) ? a0 : expm1f(a0);
  a1 = (a1 > 0.f) ? a1 : expm1f(a1);
  a2 = (a2 > 0.f) ? a2 : expm1f(a2);
  a3 = (a3 > 0.f) ? a3 : expm1f(a3);
  f16x4 oh, ol;
  f16 q0 = (f16)a0; oh[0] = q0; ol[0] = (f16)(a0 - (float)q0);
  f16 q1 = (f16)a1; oh[1] = q1; ol[1] = (f16)(a1 - (float)q1);
  f16 q2 = (f16)a2; oh[2] = q2; ol[2] = (f16)(a2 - (float)q2);
  f16 q3 = (f16)a3; oh[3] = q3; ol[3] = (f16)(a3 - (float)q3);
  ((f16x4*)Oh)[self] = oh;
  ((f16x4*)Ol)[self] = ol;
}

// ---------------- pooling (sorted batch -> ranges) + final linear -------------
__global__ __launch_bounds__(256) void find_start(const int* __restrict__ batch,
                                                  int* __restrict__ gstart) {
  int g = blockIdx.x * 256 + threadIdx.x;
  if (g <= NUM_GRAPHS) {
    int lo = 0, hi = N_NODES;
    while (lo < hi) {
      int mid = (lo + hi) >> 1;
      if (batch[mid] < g) lo = mid + 1; else hi = mid;
    }
    gstart[g] = lo;
  }
}

__global__ __launch_bounds__(256) void pool_final(
    const f16* __restrict__ Hh, const f16* __restrict__ Hl,
    const int* __restrict__ gstart,
    const float* __restrict__ W, const float* __restrict__ b,
    float* __restrict__ out) {
  int g = blockIdx.x;
  __shared__ float part[NCLS * 256];
  int f = threadIdx.x;
  int s = gstart[g], e = gstart[g + 1];
  float sum = 0.f;
  for (int n = s; n < e; ++n) {
    size_t o = (size_t)n * HID + f;
    sum += (float)Hh[o] + (float)Hl[o];
  }
  float v = sum / fmaxf((float)(e - s), 1.0f);
#pragma unroll
  for (int c = 0; c < NCLS; ++c) part[c * 256 + f] = v * W[f * NCLS + c];
  __syncthreads();
  for (int off = 128; off > 0; off >>= 1) {
    if (f < off) {
#pragma unroll
      for (int c = 0; c < NCLS; ++c) part[c * 256 + f] += part[c * 256 + f + off];
    }
    __syncthreads();
  }
  if (f < NCLS) out[g * NCLS + f] = part[f * 256] + b[f];
}

extern "C" void kernel_launch(void* const* d_in, const int* in_sizes, int n_in,
                              void* d_out, int out_size, void* d_ws, size_t ws_size,
                              hipStream_t stream) {
  const float* x = (const float*)d_in[0];
  const int* ei = (const int*)d_in[1];
  const int* e_src = ei;
  const int* e_dst = ei + N_EDGES;
  const float* ea = (const float*)d_in[2];
  // d_in[3] = edge_type: unused (edge_dim=1 mixing carries no per-type params)
  const int* batch = (const int*)d_in[4];
  const float* enc1_w = (const float*)d_in[5];
  const float* enc1_b = (const float*)d_in[6];
  const float* enc2_w = (const float*)d_in[7];
  const float* enc2_b = (const float*)d_in[8];
  const float* conv_ws = (const float*)d_in[9];
  const float* conv_bs = (const float*)d_in[10];
  const float* lin1_w = (const float*)d_in[11];
  const float* lin1_b = (const float*)d_in[12];
  float* out = (float*)d_out;

  char* w = (char*)d_ws;
  size_t off = 0;
  auto alloc = [&](size_t bytes) {
    size_t o = off;
    off = (off + bytes + 255) & ~(size_t)255;
    return (void*)(w + o);
  };
  const size_t PLANE = (size_t)N_NODES * HID;  // 12.8M f16 elements
  f16* Ahp = (f16*)alloc(PLANE * 2);
  f16* Alp = (f16*)alloc(PLANE * 2);
  f16* Bhp = (f16*)alloc(PLANE * 2);
  f16* Blp = (f16*)alloc(PLANE * 2);
  const size_t WTOT = 16384 + 32768 + 4 * 65536;
  f16* wth = (f16*)alloc(WTOT * 2);
  f16* wtl = (f16*)alloc(WTOT * 2);
  unsigned long long* dpack = (unsigned long long*)alloc((size_t)N_NODES * 8);
  float* dinv = (float*)alloc((size_t)N_NODES * 4);
  int* row_ptr = (int*)alloc((size_t)(N_NODES + 1) * 4);
  int* cursor = (int*)alloc((size_t)N_NODES * 4);
  int* bsum = (int*)alloc((size_t)256 * 4);
  int* csr_src = (int*)alloc((size_t)N_EDGES * 4);
  float* csr_coef = (float*)alloc((size_t)N_EDGES * 4);
  int* gstart = (int*)alloc((size_t)(NUM_GRAPHS + 1) * 4);
  (void)ws_size; (void)in_sizes; (void)n_in; (void)out_size;

  hipMemsetAsync(dpack, 0, (size_t)N_NODES * 8, stream);
  hipMemsetAsync(cursor, 0, (size_t)N_NODES * 4, stream);

  const int nb_nodes = (N_NODES + 255) / 256;
  const int nb_edges = (N_EDGES + 255) / 256;

  // graph normalization + CSR (feature-independent)
  deg_accum<<<nb_edges, 256, 0, stream>>>(e_dst, ea, dpack, N_EDGES);
  scan_p1<<<nb_nodes, 256, 0, stream>>>(dpack, dinv, bsum, N_NODES);
  scan_p2<<<1, 256, 0, stream>>>(bsum, nb_nodes, row_ptr + N_NODES);
  scan_p3<<<nb_nodes, 256, 0, stream>>>(dpack, bsum, row_ptr, N_NODES);
  csr_fill<<<nb_edges, 256, 0, stream>>>(e_src, e_dst, ea, dinv, row_ptr, cursor,
                                         csr_src, csr_coef, N_EDGES);
  find_start<<<(NUM_GRAPHS + 256) / 256, 256, 0, stream>>>(batch, gstart);

  // split x into f16 planes (aliased into B planes; dead after enc1)
  f16* xh = Bhp;
  f16* xl = Blp;
  {
    int n4 = N_NODES * F_IN / 4;
    split_f32<<<(n4 + 255) / 256, 256, 0, stream>>>(x, xh, xl, n4);
  }
  // weight transpose+split
  f16* e1h = wth;            f16* e1l = wtl;
  f16* e2h = wth + 16384;    f16* e2l = wtl + 16384;
  f16* cvh = wth + 49152;    f16* cvl = wtl + 49152;
  tsplit<<<(16384 + 255) / 256, 256, 0, stream>>>(enc1_w, e1h, e1l, F_IN, F_IN, 16384);
  tsplit<<<(32768 + 255) / 256, 256, 0, stream>>>(enc2_w, e2h, e2l, F_IN, HID, 32768);
  tsplit<<<(262144 + 255) / 256, 256, 0, stream>>>(conv_ws, cvh, cvl, HID, HID, 262144);

  const int gR = (N_NODES + 127) / 128;  // 391

  // enc1: x@W1+b1 -> A planes [50000][128]
  {
    dim3 grid(gR, 1);
    gemm_mfma<<<grid, 256, 0, stream>>>(xh, xl, e1h, e1l, enc1_b,
                                        Ahp, Alp, N_NODES, F_IN, F_IN);
  }
  // enc2: h0@W2+b2 -> B planes [50000][256] (overwrites dead x region)
  {
    dim3 grid(gR, 2);
    gemm_mfma<<<grid, 256, 0, stream>>>(Ahp, Alp, e2h, e2l, enc2_b,
                                        Bhp, Blp, N_NODES, F_IN, HID);
  }

  // 4 GCN layers: hW = h@W (B->A); aggregate+bias+ELU (A->B, hi-only neighbors)
  for (int layer = 0; layer < 4; ++layer) {
    dim3 grid(gR, 2);
    gemm_mfma<<<grid, 256, 0, stream>>>(Bhp, Blp,
                                        cvh + (size_t)layer * 65536,
                                        cvl + (size_t)layer * 65536,
                                        nullptr, Ahp, Alp, N_NODES, HID, HID);
    gather_elu<<<(N_NODES + 3) / 4, 256, 0, stream>>>(
        Ahp, Alp, dinv, row_ptr, csr_src, csr_coef,
        conv_bs + (size_t)layer * HID, Bhp, Blp);
  }

  // deterministic mean-pool per graph + final linear (fused)
  pool_final<<<NUM_GRAPHS, 256, 0, stream>>>(Bhp, Blp, gstart, lin1_w, lin1_b, out);
}

// Round 11
// 670.263 us; speedup vs baseline: 1.6295x; 1.2086x over previous
//
#include <hip/hip_runtime.h>
#include <hip/hip_bf16.h>
#include <math.h>

#define N_NODES 50000
#define N_EDGES 800000
#define NUM_GRAPHS 500
#define F_IN 128
#define HID 256
#define NCLS 10

typedef _Float16 f16;
typedef _Float16 f16x8 __attribute__((ext_vector_type(8)));
typedef _Float16 f16x4 __attribute__((ext_vector_type(4)));
typedef float f32x4 __attribute__((ext_vector_type(4)));

#define LOW40 ((1ULL << 40) - 1)

// ---------------- fp32 -> (hi,lo) f16 split, elementwise (float4/thread) ------
__global__ __launch_bounds__(256) void split_f32(const float* __restrict__ in,
                                                 f16* __restrict__ hi,
                                                 f16* __restrict__ lo, int n4) {
  int i = blockIdx.x * 256 + threadIdx.x;
  if (i < n4) {
    float4 v = ((const float4*)in)[i];
    f16x4 h, l;
    f16 h0 = (f16)v.x; h[0] = h0; l[0] = (f16)(v.x - (float)h0);
    f16 h1 = (f16)v.y; h[1] = h1; l[1] = (f16)(v.y - (float)h1);
    f16 h2 = (f16)v.z; h[2] = h2; l[2] = (f16)(v.z - (float)h2);
    f16 h3 = (f16)v.w; h[3] = h3; l[3] = (f16)(v.w - (float)h3);
    ((f16x4*)hi)[i] = h;
    ((f16x4*)lo)[i] = l;
  }
}

// -------- weight transpose + split: W[b][K][Mc] -> T[b][Mc][K] (hi,lo) --------
__global__ __launch_bounds__(256) void tsplit(const float* __restrict__ W,
                                              f16* __restrict__ Th,
                                              f16* __restrict__ Tl,
                                              int K, int Mc, int total) {
  int tid = blockIdx.x * 256 + threadIdx.x;
  if (tid < total) {
    int km = K * Mc;
    int b = tid / km;
    int rem = tid - b * km;
    int m = rem / K;
    int k = rem - m * K;
    float v = W[(size_t)b * km + (size_t)k * Mc + m];
    f16 h = (f16)v;
    Th[tid] = h;
    Tl[tid] = (f16)(v - (float)h);
  }
}

// ---------------- MFMA GEMM (f16x2 emulation), LDS-staged -------------------
// C = (Ah+Al) @ (Bh+Bl) ~ ah*bh + ah*bl + al*bh ; Bt transposed [Nc][K].
// Block 256 thr = 4 waves (2x2), tile 128x128, BK=32 (one MFMA K per step).
// LDS planes [128][40] f16 (80B stride: 16B-aligned, 2-way bank alias = free).
#define LSTR 40

__global__ __launch_bounds__(256) void gemm_mfma(
    const f16* __restrict__ Ah, const f16* __restrict__ Al,
    const f16* __restrict__ Bth, const f16* __restrict__ Btl,
    const float* __restrict__ bias,
    f16* __restrict__ Ch, f16* __restrict__ Cl,
    int M, int K, int Nc) {
  __shared__ f16 Ash[128 * LSTR];
  __shared__ f16 Asl[128 * LSTR];
  __shared__ f16 Bsh[128 * LSTR];
  __shared__ f16 Bsl[128 * LSTR];
  const int t = threadIdx.x;
  const int lane = t & 63;
  const int wave = t >> 6;
  const int wm = wave >> 1;
  const int wn = wave & 1;
  const int row0 = blockIdx.x * 128 + wm * 64;
  const int col0 = blockIdx.y * 128 + wn * 64;
  const int brow0 = blockIdx.x * 128;
  const int bcol0 = blockIdx.y * 128;
  const int lr = lane & 15;
  const int kg = (lane >> 4) * 8;

  f32x4 acc[4][4];
  const f32x4 vzero = {0.f, 0.f, 0.f, 0.f};
#pragma unroll
  for (int m = 0; m < 4; ++m)
#pragma unroll
    for (int n = 0; n < 4; ++n) acc[m][n] = vzero;

  // staging map: idx in [0,512): row = idx>>2 (0..127), q8 = (idx&3)*8 f16
  const int srow = t >> 2;
  const int sq8 = (t & 3) * 8;
  int arow = brow0 + srow; if (arow > M - 1) arow = M - 1;
  int arow2 = brow0 + srow + 64; if (arow2 > M - 1) arow2 = M - 1;
  // second iteration (idx = t+256): row = srow+64, same q8
  const size_t gA0 = (size_t)arow * K + sq8;
  const size_t gA1 = (size_t)arow2 * K + sq8;
  const size_t gB0 = (size_t)(bcol0 + srow) * K + sq8;
  const size_t gB1 = (size_t)(bcol0 + srow + 64) * K + sq8;
  const int l0 = srow * LSTR + sq8;
  const int l1 = (srow + 64) * LSTR + sq8;

#pragma unroll 1
  for (int k0 = 0; k0 < K; k0 += 32) {
    // ---- stage A,B k-slab (coalesced 16B/thread x2 per plane) ----
    f16x8 va0 = *(const f16x8*)(Ah + gA0 + k0);
    f16x8 va1 = *(const f16x8*)(Ah + gA1 + k0);
    f16x8 wa0 = *(const f16x8*)(Al + gA0 + k0);
    f16x8 wa1 = *(const f16x8*)(Al + gA1 + k0);
    f16x8 vb0 = *(const f16x8*)(Bth + gB0 + k0);
    f16x8 vb1 = *(const f16x8*)(Bth + gB1 + k0);
    f16x8 wb0 = *(const f16x8*)(Btl + gB0 + k0);
    f16x8 wb1 = *(const f16x8*)(Btl + gB1 + k0);
    *(f16x8*)(Ash + l0) = va0;
    *(f16x8*)(Ash + l1) = va1;
    *(f16x8*)(Asl + l0) = wa0;
    *(f16x8*)(Asl + l1) = wa1;
    *(f16x8*)(Bsh + l0) = vb0;
    *(f16x8*)(Bsh + l1) = vb1;
    *(f16x8*)(Bsl + l0) = wb0;
    *(f16x8*)(Bsl + l1) = wb1;
    __syncthreads();
    // ---- fragments from LDS + 48 MFMA ----
    f16x8 ah[4], al[4], bh[4], bl[4];
    const int abase = wm * 64 + lr;
    const int bbase = wn * 64 + lr;
#pragma unroll
    for (int m = 0; m < 4; ++m) {
      ah[m] = *(const f16x8*)(Ash + (abase + m * 16) * LSTR + kg);
      al[m] = *(const f16x8*)(Asl + (abase + m * 16) * LSTR + kg);
    }
#pragma unroll
    for (int n = 0; n < 4; ++n) {
      bh[n] = *(const f16x8*)(Bsh + (bbase + n * 16) * LSTR + kg);
      bl[n] = *(const f16x8*)(Bsl + (bbase + n * 16) * LSTR + kg);
    }
#pragma unroll
    for (int m = 0; m < 4; ++m)
#pragma unroll
      for (int n = 0; n < 4; ++n) {
        acc[m][n] = __builtin_amdgcn_mfma_f32_16x16x32_f16(ah[m], bh[n], acc[m][n], 0, 0, 0);
        acc[m][n] = __builtin_amdgcn_mfma_f32_16x16x32_f16(ah[m], bl[n], acc[m][n], 0, 0, 0);
        acc[m][n] = __builtin_amdgcn_mfma_f32_16x16x32_f16(al[m], bh[n], acc[m][n], 0, 0, 0);
      }
    __syncthreads();
  }

  const int rbase = (lane >> 4) * 4;
#pragma unroll
  for (int m = 0; m < 4; ++m) {
#pragma unroll
    for (int r = 0; r < 4; ++r) {
      int row = row0 + m * 16 + rbase + r;
      if (row < M) {
#pragma unroll
        for (int n = 0; n < 4; ++n) {
          int col = col0 + n * 16 + lr;
          float v = acc[m][n][r];
          if (bias) v += bias[col];
          f16 h = (f16)v;
          size_t o = (size_t)row * Nc + col;
          Ch[o] = h;
          Cl[o] = (f16)(v - (float)h);
        }
      }
    }
  }
}

// ------- degree accumulation: ONE packed u64 atomic per edge ----------------
__global__ __launch_bounds__(256) void deg_accum(
    const int* __restrict__ dst, const float* __restrict__ ew,
    unsigned long long* __restrict__ dpack, int E) {
  int e = blockIdx.x * 256 + threadIdx.x;
  if (e < E) {
    unsigned long long v = (1ULL << 40) |
        (unsigned long long)(unsigned)(ew[e] * 16777216.0f + 0.5f);
    atomicAdd(&dpack[dst[e]], v);
  }
}

// ---------------- hierarchical exclusive scan + dinv (from packed) -----------
__global__ __launch_bounds__(256) void scan_p1(
    const unsigned long long* __restrict__ dpack,
    float* __restrict__ dinv, int* __restrict__ bsum, int n) {
  __shared__ int s[256];
  int i = blockIdx.x * 256 + threadIdx.x;
  int c = 0;
  if (i < n) {
    unsigned long long v = dpack[i];
    c = (int)(v >> 40);
    float d = (float)(v & LOW40) * (1.0f / 16777216.0f);
    dinv[i] = rsqrtf(d + 1.0f);
  }
  s[threadIdx.x] = c;
  __syncthreads();
  for (int off = 128; off > 0; off >>= 1) {
    if (threadIdx.x < off) s[threadIdx.x] += s[threadIdx.x + off];
    __syncthreads();
  }
  if (threadIdx.x == 0) bsum[blockIdx.x] = s[0];
}

__global__ __launch_bounds__(256) void scan_p2(int* __restrict__ bsum, int nb,
                                               int* __restrict__ total_out) {
  __shared__ int s[256];
  int t = threadIdx.x;
  int v = (t < nb) ? bsum[t] : 0;
  s[t] = v;
  __syncthreads();
  for (int off = 1; off < 256; off <<= 1) {
    int u = (t >= off) ? s[t - off] : 0;
    __syncthreads();
    s[t] += u;
    __syncthreads();
  }
  if (t < nb) bsum[t] = s[t] - v;
  if (t == 255) *total_out = s[255];
}

__global__ __launch_bounds__(256) void scan_p3(
    const unsigned long long* __restrict__ dpack,
    const int* __restrict__ bsum, int* __restrict__ row_ptr, int n) {
  __shared__ int s[256];
  int i = blockIdx.x * 256 + threadIdx.x;
  int t = threadIdx.x;
  int v = (i < n) ? (int)(dpack[i] >> 40) : 0;
  s[t] = v;
  __syncthreads();
  for (int off = 1; off < 256; off <<= 1) {
    int u = (t >= off) ? s[t - off] : 0;
    __syncthreads();
    s[t] += u;
    __syncthreads();
  }
  if (i < n) row_ptr[i] = bsum[blockIdx.x] + s[t] - v;
}

// ---------------- CSR fill ----------------
__global__ __launch_bounds__(256) void csr_fill(
    const int* __restrict__ src, const int* __restrict__ dst,
    const float* __restrict__ ew, const float* __restrict__ dinv,
    const int* __restrict__ row_ptr, int* cursor,
    int* __restrict__ csr_src, float* __restrict__ csr_coef, int E) {
  int e = blockIdx.x * 256 + threadIdx.x;
  if (e < E) {
    int s = src[e], d = dst[e];
    int pos = atomicAdd(&cursor[d], 1);
    int idx = row_ptr[d] + pos;
    csr_src[idx] = s;
    csr_coef[idx] = dinv[s] * ew[e] * dinv[d];
  }
}

// -- aggregation + bias + ELU: neighbors read HI PLANE ONLY (halves traffic) --
__global__ __launch_bounds__(256) void gather_elu(
    const f16* __restrict__ Hh, const f16* __restrict__ Hl,
    const float* __restrict__ dinv, const int* __restrict__ row_ptr,
    const int* __restrict__ csr_src, const float* __restrict__ csr_coef,
    const float* __restrict__ bias,
    f16* __restrict__ Oh, f16* __restrict__ Ol) {
  const int wave = threadIdx.x >> 6;
  const int lane = threadIdx.x & 63;
  const int n = blockIdx.x * 4 + wave;
  if (n >= N_NODES) return;
  const f16x4* hh4 = (const f16x4*)Hh;
  const int start = row_ptr[n], end = row_ptr[n + 1];
  const float di = dinv[n];
  const float cself = di * di;
  size_t self = (size_t)n * 64 + lane;
  f16x4 sh = hh4[self];
  f16x4 sl = ((const f16x4*)Hl)[self];
  float a0 = cself * ((float)sh[0] + (float)sl[0]);
  float a1 = cself * ((float)sh[1] + (float)sl[1]);
  float a2 = cself * ((float)sh[2] + (float)sl[2]);
  float a3 = cself * ((float)sh[3] + (float)sl[3]);
  const int npairs = (end - start) >> 1;
  int e = start;
  if (npairs > 0) {
    int s0 = csr_src[e], s1 = csr_src[e + 1];
    float w0 = csr_coef[e], w1 = csr_coef[e + 1];
    for (int p = 1; p < npairs; ++p) {
      e += 2;
      f16x4 v0 = hh4[(size_t)s0 * 64 + lane];
      f16x4 v1 = hh4[(size_t)s1 * 64 + lane];
      int t0 = csr_src[e], t1 = csr_src[e + 1];
      float u0 = csr_coef[e], u1 = csr_coef[e + 1];
      a0 += w0 * (float)v0[0] + w1 * (float)v1[0];
      a1 += w0 * (float)v0[1] + w1 * (float)v1[1];
      a2 += w0 * (float)v0[2] + w1 * (float)v1[2];
      a3 += w0 * (float)v0[3] + w1 * (float)v1[3];
      s0 = t0; s1 = t1; w0 = u0; w1 = u1;
    }
    f16x4 v0 = hh4[(size_t)s0 * 64 + lane];
    f16x4 v1 = hh4[(size_t)s1 * 64 + lane];
    a0 += w0 * (float)v0[0] + w1 * (float)v1[0];
    a1 += w0 * (float)v0[1] + w1 * (float)v1[1];
    a2 += w0 * (float)v0[2] + w1 * (float)v1[2];
    a3 += w0 * (float)v0[3] + w1 * (float)v1[3];
    e += 2;
  }
  if (e < end) {
    int s0 = csr_src[e];
    float w0 = csr_coef[e];
    f16x4 v0 = hh4[(size_t)s0 * 64 + lane];
    a0 += w0 * (float)v0[0];
    a1 += w0 * (float)v0[1];
    a2 += w0 * (float)v0[2];
    a3 += w0 * (float)v0[3];
  }
  float4 bb = ((const float4*)bias)[lane];
  a0 += bb.x; a1 += bb.y; a2 += bb.z; a3 += bb.w;
  a0 = (a0 > 0.f) ? a0 : expm1f(a0);
  a1 = (a1 > 0.f) ? a1 : expm1f(a1);
  a2 = (a2 > 0.f) ? a2 : expm1f(a2);
  a3 = (a3 > 0.f) ? a3 : expm1f(a3);
  f16x4 oh, ol;
  f16 q0 = (f16)a0; oh[0] = q0; ol[0] = (f16)(a0 - (float)q0);
  f16 q1 = (f16)a1; oh[1] = q1; ol[1] = (f16)(a1 - (float)q1);
  f16 q2 = (f16)a2; oh[2] = q2; ol[2] = (f16)(a2 - (float)q2);
  f16 q3 = (f16)a3; oh[3] = q3; ol[3] = (f16)(a3 - (float)q3);
  ((f16x4*)Oh)[self] = oh;
  ((f16x4*)Ol)[self] = ol;
}

// ---------------- pooling (sorted batch -> ranges) + final linear -------------
__global__ __launch_bounds__(256) void find_start(const int* __restrict__ batch,
                                                  int* __restrict__ gstart) {
  int g = blockIdx.x * 256 + threadIdx.x;
  if (g <= NUM_GRAPHS) {
    int lo = 0, hi = N_NODES;
    while (lo < hi) {
      int mid = (lo + hi) >> 1;
      if (batch[mid] < g) lo = mid + 1; else hi = mid;
    }
    gstart[g] = lo;
  }
}

__global__ __launch_bounds__(256) void pool_final(
    const f16* __restrict__ Hh, const f16* __restrict__ Hl,
    const int* __restrict__ gstart,
    const float* __restrict__ W, const float* __restrict__ b,
    float* __restrict__ out) {
  int g = blockIdx.x;
  __shared__ float part[NCLS * 256];
  int f = threadIdx.x;
  int s = gstart[g], e = gstart[g + 1];
  float sum = 0.f;
  for (int n = s; n < e; ++n) {
    size_t o = (size_t)n * HID + f;
    sum += (float)Hh[o] + (float)Hl[o];
  }
  float v = sum / fmaxf((float)(e - s), 1.0f);
#pragma unroll
  for (int c = 0; c < NCLS; ++c) part[c * 256 + f] = v * W[f * NCLS + c];
  __syncthreads();
  for (int off = 128; off > 0; off >>= 1) {
    if (f < off) {
#pragma unroll
      for (int c = 0; c < NCLS; ++c) part[c * 256 + f] += part[c * 256 + f + off];
    }
    __syncthreads();
  }
  if (f < NCLS) out[g * NCLS + f] = part[f * 256] + b[f];
}

extern "C" void kernel_launch(void* const* d_in, const int* in_sizes, int n_in,
                              void* d_out, int out_size, void* d_ws, size_t ws_size,
                              hipStream_t stream) {
  const float* x = (const float*)d_in[0];
  const int* ei = (const int*)d_in[1];
  const int* e_src = ei;
  const int* e_dst = ei + N_EDGES;
  const float* ea = (const float*)d_in[2];
  const int* batch = (const int*)d_in[4];
  const float* enc1_w = (const float*)d_in[5];
  const float* enc1_b = (const float*)d_in[6];
  const float* enc2_w = (const float*)d_in[7];
  const float* enc2_b = (const float*)d_in[8];
  const float* conv_ws = (const float*)d_in[9];
  const float* conv_bs = (const float*)d_in[10];
  const float* lin1_w = (const float*)d_in[11];
  const float* lin1_b = (const float*)d_in[12];
  float* out = (float*)d_out;

  char* w = (char*)d_ws;
  size_t off = 0;
  auto alloc = [&](size_t bytes) {
    size_t o = off;
    off = (off + bytes + 255) & ~(size_t)255;
    return (void*)(w + o);
  };
  const size_t PLANE = (size_t)N_NODES * HID;
  f16* Ahp = (f16*)alloc(PLANE * 2);
  f16* Alp = (f16*)alloc(PLANE * 2);
  f16* Bhp = (f16*)alloc(PLANE * 2);
  f16* Blp = (f16*)alloc(PLANE * 2);
  const size_t WTOT = 16384 + 32768 + 4 * 65536;
  f16* wth = (f16*)alloc(WTOT * 2);
  f16* wtl = (f16*)alloc(WTOT * 2);
  unsigned long long* dpack = (unsigned long long*)alloc((size_t)N_NODES * 8);
  float* dinv = (float*)alloc((size_t)N_NODES * 4);
  int* row_ptr = (int*)alloc((size_t)(N_NODES + 1) * 4);
  int* cursor = (int*)alloc((size_t)N_NODES * 4);
  int* bsum = (int*)alloc((size_t)256 * 4);
  int* csr_src = (int*)alloc((size_t)N_EDGES * 4);
  float* csr_coef = (float*)alloc((size_t)N_EDGES * 4);
  int* gstart = (int*)alloc((size_t)(NUM_GRAPHS + 1) * 4);
  (void)ws_size; (void)in_sizes; (void)n_in; (void)out_size;

  hipMemsetAsync(dpack, 0, (size_t)N_NODES * 8, stream);
  hipMemsetAsync(cursor, 0, (size_t)N_NODES * 4, stream);

  const int nb_nodes = (N_NODES + 255) / 256;
  const int nb_edges = (N_EDGES + 255) / 256;

  // graph normalization + CSR (feature-independent)
  deg_accum<<<nb_edges, 256, 0, stream>>>(e_dst, ea, dpack, N_EDGES);
  scan_p1<<<nb_nodes, 256, 0, stream>>>(dpack, dinv, bsum, N_NODES);
  scan_p2<<<1, 256, 0, stream>>>(bsum, nb_nodes, row_ptr + N_NODES);
  scan_p3<<<nb_nodes, 256, 0, stream>>>(dpack, bsum, row_ptr, N_NODES);
  csr_fill<<<nb_edges, 256, 0, stream>>>(e_src, e_dst, ea, dinv, row_ptr, cursor,
                                         csr_src, csr_coef, N_EDGES);
  find_start<<<(NUM_GRAPHS + 256) / 256, 256, 0, stream>>>(batch, gstart);

  // split x into f16 planes (aliased into B planes; dead after enc1)
  f16* xh = Bhp;
  f16* xl = Blp;
  {
    int n4 = N_NODES * F_IN / 4;
    split_f32<<<(n4 + 255) / 256, 256, 0, stream>>>(x, xh, xl, n4);
  }
  // weight transpose+split
  f16* e1h = wth;            f16* e1l = wtl;
  f16* e2h = wth + 16384;    f16* e2l = wtl + 16384;
  f16* cvh = wth + 49152;    f16* cvl = wtl + 49152;
  tsplit<<<(16384 + 255) / 256, 256, 0, stream>>>(enc1_w, e1h, e1l, F_IN, F_IN, 16384);
  tsplit<<<(32768 + 255) / 256, 256, 0, stream>>>(enc2_w, e2h, e2l, F_IN, HID, 32768);
  tsplit<<<(262144 + 255) / 256, 256, 0, stream>>>(conv_ws, cvh, cvl, HID, HID, 262144);

  const int gR = (N_NODES + 127) / 128;  // 391

  // enc1: x@W1+b1 -> A planes [50000][128]
  {
    dim3 grid(gR, 1);
    gemm_mfma<<<grid, 256, 0, stream>>>(xh, xl, e1h, e1l, enc1_b,
                                        Ahp, Alp, N_NODES, F_IN, F_IN);
  }
  // enc2: h0@W2+b2 -> B planes [50000][256] (overwrites dead x region)
  {
    dim3 grid(gR, 2);
    gemm_mfma<<<grid, 256, 0, stream>>>(Ahp, Alp, e2h, e2l, enc2_b,
                                        Bhp, Blp, N_NODES, F_IN, HID);
  }

  // 4 GCN layers: hW = h@W (B->A); aggregate+bias+ELU (A->B, hi-only neighbors)
  for (int layer = 0; layer < 4; ++layer) {
    dim3 grid(gR, 2);
    gemm_mfma<<<grid, 256, 0, stream>>>(Bhp, Blp,
                                        cvh + (size_t)layer * 65536,
                                        cvl + (size_t)layer * 65536,
                                        nullptr, Ahp, Alp, N_NODES, HID, HID);
    gather_elu<<<(N_NODES + 3) / 4, 256, 0, stream>>>(
        Ahp, Alp, dinv, row_ptr, csr_src, csr_coef,
        conv_bs + (size_t)layer * HID, Bhp, Blp);
  }

  // deterministic mean-pool per graph + final linear (fused)
  pool_final<<<NUM_GRAPHS, 256, 0, stream>>>(Bhp, Blp, gstart, lin1_w, lin1_b, out);
}